// Round 20
// baseline (175.175 us; speedup 1.0000x reference)
//
#include <hip/hip_runtime.h>
#include <hip/hip_fp16.h>
#include <hip/hip_fp8.h>

#define IN_CH  128
#define HID_CH 64
#define OUT_CH 8
#define BSH    8        // 256 nodes per bucket
#define BCAP   8960     // per-bucket edge capacity
#define PCHUNK 8192     // edges per partition block

typedef unsigned long long ull;
typedef float floatx2 __attribute__((ext_vector_type(2)));
typedef _Float16 f16x8 __attribute__((ext_vector_type(8)));
typedef float f32x4 __attribute__((ext_vector_type(4)));

// edge_index arrives as int32. src = ei[0..E), dst = ei[E..2E).
// packed edge: low bits = src, bits 24..31 = dst & 255

__device__ __forceinline__ unsigned char f2fp8(float f) {
    __hip_fp8_e4m3 t(f);
    return (unsigned char)t.__x;
}
__device__ __forceinline__ float fp82f(unsigned char b) {
    __hip_fp8_e4m3 t;
    t.__x = (__hip_fp8_storage_t)b;
    return (float)t;
}

// unpack 8 fp8 bytes -> 8 floats via packed HW converts
__device__ __forceinline__ void acc8(float* acc, ull p) {
#if __has_builtin(__builtin_amdgcn_cvt_pk_f32_fp8)
    unsigned lo = (unsigned)p, hi = (unsigned)(p >> 32);
    floatx2 q0 = __builtin_amdgcn_cvt_pk_f32_fp8(lo, false);
    floatx2 q1 = __builtin_amdgcn_cvt_pk_f32_fp8(lo, true);
    floatx2 q2 = __builtin_amdgcn_cvt_pk_f32_fp8(hi, false);
    floatx2 q3 = __builtin_amdgcn_cvt_pk_f32_fp8(hi, true);
    acc[0] += q0.x; acc[1] += q0.y; acc[2] += q1.x; acc[3] += q1.y;
    acc[4] += q2.x; acc[5] += q2.y; acc[6] += q3.x; acc[7] += q3.y;
#else
#pragma unroll
    for (int j = 0; j < 8; ++j) acc[j] += fp82f((unsigned char)(p >> (8 * j)));
#endif
}

// ---------- 1. coarse partition into 256-node buckets (dense-run writes) ----------
__global__ __launch_bounds__(512) void part_k(const int* __restrict__ ei, int E, int NB,
                                              int* __restrict__ gcnt,
                                              unsigned* __restrict__ bucket) {
    __shared__ int cnt[512];
    __shared__ int scn[512];
    __shared__ int gbase[512];
    __shared__ unsigned ordered[PCHUNK];        // 32 KB
    __shared__ unsigned short ordK[PCHUNK];     // 16 KB: bucket id per slot
    int t = threadIdx.x;
    int c0 = blockIdx.x * PCHUNK;
    const int* __restrict__ src = ei;
    const int* __restrict__ dst = ei + E;

    cnt[t] = 0;
    __syncthreads();
    for (int i = t; i < PCHUNK; i += 512) {
        int e = c0 + i;
        if (e < E) atomicAdd(&cnt[dst[e] >> BSH], 1);
    }
    __syncthreads();
    scn[t] = cnt[t];
    __syncthreads();
    for (int o = 1; o < 512; o <<= 1) {
        int v = (t >= o) ? scn[t - o] : 0;
        __syncthreads();
        scn[t] += v;
        __syncthreads();
    }
    int ex = scn[t] - cnt[t];
    __syncthreads();
    scn[t] = ex;                             // exclusive scan
    int cn = cnt[t];
    gbase[t] = (t < NB && cn > 0) ? atomicAdd(&gcnt[t], cn) : 0;
    __syncthreads();
    cnt[t] = 0;
    __syncthreads();
    for (int i = t; i < PCHUNK; i += 512) {
        int e = c0 + i;
        if (e < E) {
            int s = src[e], d = dst[e];
            int k = d >> BSH;
            int slot = scn[k] + atomicAdd(&cnt[k], 1);
            ordered[slot] = (unsigned)s | ((unsigned)(d & 255) << 24);
            ordK[slot] = (unsigned short)k;
        }
    }
    __syncthreads();
    int tot = scn[511] + cnt[511];
    for (int i = t; i < tot; i += 512) {
        int k = ordK[i];
        bucket[(size_t)k * BCAP + gbase[k] + (i - scn[k])] = ordered[i];
    }
}

// ---------- 2. per-bucket: degree count + LDS counting sort -> dense CSR ----------
__global__ __launch_bounds__(256) void sort_k(unsigned* __restrict__ bucket,
                                              const int* __restrict__ gcnt,
                                              int* __restrict__ deg,
                                              float* __restrict__ dinv,
                                              int* __restrict__ off, int n) {
    __shared__ int cnt[256];
    __shared__ int excl[256];
    __shared__ int cur[256];
    __shared__ int ordered[BCAP];            // 35 KB
    int bk = blockIdx.x;
    int t = threadIdx.x;
    int node0 = bk << BSH;
    cnt[t] = 0;
    __syncthreads();
    int ecnt = gcnt[bk];
    unsigned* __restrict__ bb = bucket + (size_t)bk * BCAP;
    for (int i = t; i < ecnt; i += 256) {
        unsigned p = bb[i];
        atomicAdd(&cnt[p >> 24], 1);
    }
    __syncthreads();
    int dg = cnt[t];
    excl[t] = dg;
    __syncthreads();
    for (int o = 1; o < 256; o <<= 1) {
        int v = (t >= o) ? excl[t - o] : 0;
        __syncthreads();
        excl[t] += v;
        __syncthreads();
    }
    int ex = excl[t] - dg;                   // exclusive
    __syncthreads();
    excl[t] = ex;
    cur[t] = 0;
    int node = node0 + t;
    if (node < n) {
        deg[node]  = dg;
        dinv[node] = rsqrtf((float)dg + 1.0f);   // +1 self-loop
        off[node]  = bk * BCAP + ex;             // csr int-index base
    }
    __syncthreads();
    for (int i = t; i < ecnt; i += 256) {
        unsigned p = bb[i];
        int s = (int)(p & 0xFFFFFFu), d = (int)(p >> 24);
        int slot = excl[d] + atomicAdd(&cur[d], 1);
        ordered[slot] = s;
    }
    __syncthreads();
    int* __restrict__ csr = (int*)bb;
    for (int i = t; i < ecnt; i += 256) csr[i] = ordered[i];
}

// ---------- 3. h1' = dinv * (x @ W1) -> fp8, via MFMA f16 ----------
#define LDK 136
__global__ __launch_bounds__(256) void gemm1_k(const float* __restrict__ x,
                                               const float* __restrict__ W,
                                               const float* __restrict__ dinv,
                                               unsigned char* __restrict__ h, int n) {
    __shared__ __align__(16) float uShared[64 * 68];   // xs f16 overlay, then outS f32
    __shared__ __align__(16) _Float16 Wt[64 * LDK];    // W^T f16
    int t = threadIdx.x;
    int node0 = blockIdx.x * 64;
    _Float16* xs = (_Float16*)uShared;

    for (int i = t; i < 64 * 32; i += 256) {
        int row = i >> 5, c4 = i & 31;
        int node = node0 + row;
        float4 v = (node < n) ? *(const float4*)(x + (size_t)node * IN_CH + c4 * 4)
                              : make_float4(0.f, 0.f, 0.f, 0.f);
        _Float16* dstp = xs + row * LDK + c4 * 4;
        dstp[0] = (_Float16)v.x; dstp[1] = (_Float16)v.y;
        dstp[2] = (_Float16)v.z; dstp[3] = (_Float16)v.w;
    }
    for (int i = t; i < IN_CH * HID_CH; i += 256) {
        int k = i >> 6, nn = i & 63;
        Wt[nn * LDK + k] = (_Float16)W[i];
    }
    __syncthreads();

    int w = t >> 6, lane = t & 63;
    int rsel = lane & 15, ksel = lane >> 4;
    f32x4 acc[4];
#pragma unroll
    for (int ct = 0; ct < 4; ++ct) acc[ct] = (f32x4){0.f, 0.f, 0.f, 0.f};

#pragma unroll
    for (int kk = 0; kk < 4; ++kk) {
        f16x8 a = *(const f16x8*)(xs + (16 * w + rsel) * LDK + kk * 32 + ksel * 8);
#pragma unroll
        for (int ct = 0; ct < 4; ++ct) {
            f16x8 b = *(const f16x8*)(Wt + (ct * 16 + rsel) * LDK + kk * 32 + ksel * 8);
            acc[ct] = __builtin_amdgcn_mfma_f32_16x16x32_f16(a, b, acc[ct], 0, 0, 0);
        }
    }
    __syncthreads();
    float* outS = uShared;
#pragma unroll
    for (int ct = 0; ct < 4; ++ct)
#pragma unroll
        for (int r = 0; r < 4; ++r)
            outS[(16 * w + ksel * 4 + r) * 68 + ct * 16 + rsel] = acc[ct][r];
    __syncthreads();

    {
        int row = t >> 2, quad = t & 3;
        int node = node0 + row;
        if (node < n) {
            float dv = dinv[node];
            const float* srcp = outS + row * 68 + quad * 16;
            unsigned un[4];
#pragma unroll
            for (int g = 0; g < 4; ++g) {
                unsigned v = 0;
#pragma unroll
                for (int j = 0; j < 4; ++j)
                    v |= (unsigned)f2fp8(srcp[g * 4 + j] * dv) << (8 * j);
                un[g] = v;
            }
            *(uint4*)(h + (size_t)node * HID_CH + quad * 16) = make_uint4(un[0], un[1], un[2], un[3]);
        }
    }
}

// ---------- 4. fused layer-1 gather + bias + relu + gemm2 -> h2 fp16 ----------
// Gather = R16's e8 x cg8 core. Epilogue: each lane computes the gemm2 partial
// for OUTPUT channel e8 over k-rows cg*8..cg*8+7 with W2/b1 in REGISTERS
// (8+8 scalar global loads from a 2KB L1-resident table; zero LDS, zero conflicts).
__global__ __launch_bounds__(256) void agg1_fused_k(const int* __restrict__ off,
                                                    const int* __restrict__ deg,
                                                    const int* __restrict__ csr,
                                                    const float* __restrict__ dinv,
                                                    const unsigned char* __restrict__ h,
                                                    const float* __restrict__ b1,
                                                    const float* __restrict__ W2,
                                                    __half* __restrict__ h2, int n) {
    int tid = threadIdx.x;
    int node = blockIdx.x * 4 + (tid >> 6);
    if (node >= n) return;
    int lane = tid & 63;
    int e8 = lane >> 3, cg = lane & 7;

    float acc[8];
#pragma unroll
    for (int j = 0; j < 8; ++j) acc[j] = 0.0f;

    if (e8 == 0)   // self-loop row
        acc8(acc, *(const ull*)(h + (size_t)node * HID_CH + cg * 8));

    int o = off[node], end = o + deg[node];
    int i = o + e8;
    for (; i + 24 < end; i += 32) {
        int s0 = csr[i], s1 = csr[i + 8], s2 = csr[i + 16], s3 = csr[i + 24];
        ull p0 = *(const ull*)(h + (size_t)s0 * HID_CH + cg * 8);
        ull p1 = *(const ull*)(h + (size_t)s1 * HID_CH + cg * 8);
        ull p2 = *(const ull*)(h + (size_t)s2 * HID_CH + cg * 8);
        ull p3 = *(const ull*)(h + (size_t)s3 * HID_CH + cg * 8);
        acc8(acc, p0); acc8(acc, p1); acc8(acc, p2); acc8(acc, p3);
    }
    for (; i < end; i += 8)
        acc8(acc, *(const ull*)(h + (size_t)csr[i] * HID_CH + cg * 8));

    // reduce across edge-slots: xor 8,16,32 -> every lane holds full acc[8]
#pragma unroll
    for (int j = 0; j < 8; ++j) {
        acc[j] += __shfl_xor(acc[j], 8);
        acc[j] += __shfl_xor(acc[j], 16);
        acc[j] += __shfl_xor(acc[j], 32);
    }

    // epilogue: z[j] = relu(dv*acc[j]+b1[cg*8+j]); pc = sum_j z[j]*W2[cg*8+j][e8]
    float dv = dinv[node];
    float pc = 0.0f;
#pragma unroll
    for (int j = 0; j < 8; ++j) {
        float zj = fmaxf(dv * acc[j] + b1[cg * 8 + j], 0.0f);
        pc += zj * W2[(cg * 8 + j) * OUT_CH + e8];   // register/L1, no LDS
    }
    // reduce partial over cg: xor 1,2,4
    pc += __shfl_xor(pc, 1);
    pc += __shfl_xor(pc, 2);
    pc += __shfl_xor(pc, 4);

    if (cg == 0)   // 8 lanes (e8=0..7) write 8 consecutive halfs = 16B
        h2[(size_t)node * OUT_CH + e8] = __float2half(dv * pc);
}

// ---------- 5. layer-2 gather (fp16, 4-way) + bias + log_softmax ----------
__global__ __launch_bounds__(256) void agg2_final_k(const int* __restrict__ off,
                                                    const int* __restrict__ deg,
                                                    const int* __restrict__ csr,
                                                    const float* __restrict__ dinv,
                                                    const __half* __restrict__ h2,
                                                    const float* __restrict__ b,
                                                    float* __restrict__ out, int n) {
    int tid = threadIdx.x;
    int node = blockIdx.x * 32 + (tid >> 3);
    int c = tid & 7;
    if (node >= n) return;
    float dv = dinv[node];
    int o = off[node], dg = deg[node];
    float a0 = 0, a1 = 0, a2 = 0, a3 = 0;
    int i = o, end = o + dg;
    for (; i + 3 < end; i += 4) {
        int s0 = csr[i], s1 = csr[i + 1], s2 = csr[i + 2], s3 = csr[i + 3];
        a0 += __half2float(h2[(size_t)s0 * OUT_CH + c]);
        a1 += __half2float(h2[(size_t)s1 * OUT_CH + c]);
        a2 += __half2float(h2[(size_t)s2 * OUT_CH + c]);
        a3 += __half2float(h2[(size_t)s3 * OUT_CH + c]);
    }
    for (; i < end; ++i) a0 += __half2float(h2[(size_t)csr[i] * OUT_CH + c]);
    float self = __half2float(h2[(size_t)node * OUT_CH + c]);
    float val = dv * ((a0 + a1) + (a2 + a3) + self) + b[c];
    float m = val;
    m = fmaxf(m, __shfl_xor(m, 1, 8));
    m = fmaxf(m, __shfl_xor(m, 2, 8));
    m = fmaxf(m, __shfl_xor(m, 4, 8));
    float s8 = expf(val - m);
    s8 += __shfl_xor(s8, 1, 8);
    s8 += __shfl_xor(s8, 2, 8);
    s8 += __shfl_xor(s8, 4, 8);
    out[(size_t)node * OUT_CH + c] = val - m - logf(s8);
}

extern "C" void kernel_launch(void* const* d_in, const int* in_sizes, int n_in,
                              void* d_out, int out_size, void* d_ws, size_t ws_size,
                              hipStream_t stream) {
    const float* x  = (const float*)d_in[0];
    const int*   ei = (const int*)d_in[1];
    const float* W1 = (const float*)d_in[2];
    const float* b1 = (const float*)d_in[3];
    const float* W2 = (const float*)d_in[4];
    const float* b2 = (const float*)d_in[5];
    float* out = (float*)d_out;

    const int n = in_sizes[0] / IN_CH;      // 100000
    const int E = in_sizes[1] / 2;          // 3200000
    const int NP = 100352;
    const int NB = (n + 255) >> BSH;        // 391 buckets

    // ---- workspace layout (~22 MB) ----
    int*      deg    = (int*)d_ws;                              // [NP]
    float*    dinv   = (float*)(deg + NP);                      // [NP]
    int*      gcnt   = (int*)(dinv + NP);                       // [512]
    int*      off    = gcnt + 512;                              // [NP]
    unsigned* bucket = (unsigned*)(off + NP);                   // [NB*BCAP] u32 = 14 MB
    unsigned char* h1 = (unsigned char*)(bucket + (size_t)NB * BCAP); // [NP*64] fp8
    __half*   h2     = (__half*)(h1 + (size_t)NP * HID_CH);     // [NP*8] fp16
    int*      csr    = (int*)bucket;                            // sorted src ids after sort_k

    const int NCH = (E + PCHUNK - 1) / PCHUNK;                  // 391 partition blocks

    hipMemsetAsync(gcnt, 0, 512 * sizeof(int), stream);
    part_k<<<NCH, 512, 0, stream>>>(ei, E, NB, gcnt, bucket);
    sort_k<<<NB, 256, 0, stream>>>(bucket, gcnt, deg, dinv, off, n);
    gemm1_k<<<(n + 63) / 64, 256, 0, stream>>>(x, W1, dinv, h1, n);
    agg1_fused_k<<<(n + 3) / 4, 256, 0, stream>>>(off, deg, csr, dinv, h1, b1, W2, h2, n);
    agg2_final_k<<<(n + 31) / 32, 256, 0, stream>>>(off, deg, csr, dinv, h2, b2, out, n);
}

// Round 21
// 158.429 us; speedup vs baseline: 1.1057x; 1.1057x over previous
//
#include <hip/hip_runtime.h>
#include <hip/hip_fp16.h>
#include <hip/hip_fp8.h>

#define IN_CH  128
#define HID_CH 64
#define OUT_CH 8
#define BSH    8        // 256 nodes per bucket
#define BCAP   8960     // per-bucket edge capacity
#define PCHUNK 8192     // edges per partition block

typedef unsigned long long ull;
typedef float floatx2 __attribute__((ext_vector_type(2)));
typedef _Float16 f16x8 __attribute__((ext_vector_type(8)));
typedef float f32x4 __attribute__((ext_vector_type(4)));

// edge_index arrives as int32. src = ei[0..E), dst = ei[E..2E).
// packed edge: low bits = src, bits 24..31 = dst & 255

__device__ __forceinline__ unsigned char f2fp8(float f) {
    __hip_fp8_e4m3 t(f);
    return (unsigned char)t.__x;
}
__device__ __forceinline__ float fp82f(unsigned char b) {
    __hip_fp8_e4m3 t;
    t.__x = (__hip_fp8_storage_t)b;
    return (float)t;
}

// unpack 8 fp8 bytes -> 8 floats via packed HW converts
__device__ __forceinline__ void acc8(float* acc, ull p) {
#if __has_builtin(__builtin_amdgcn_cvt_pk_f32_fp8)
    unsigned lo = (unsigned)p, hi = (unsigned)(p >> 32);
    floatx2 q0 = __builtin_amdgcn_cvt_pk_f32_fp8(lo, false);
    floatx2 q1 = __builtin_amdgcn_cvt_pk_f32_fp8(lo, true);
    floatx2 q2 = __builtin_amdgcn_cvt_pk_f32_fp8(hi, false);
    floatx2 q3 = __builtin_amdgcn_cvt_pk_f32_fp8(hi, true);
    acc[0] += q0.x; acc[1] += q0.y; acc[2] += q1.x; acc[3] += q1.y;
    acc[4] += q2.x; acc[5] += q2.y; acc[6] += q3.x; acc[7] += q3.y;
#else
#pragma unroll
    for (int j = 0; j < 8; ++j) acc[j] += fp82f((unsigned char)(p >> (8 * j)));
#endif
}

// ---------- 1. coarse partition into 256-node buckets (dense-run writes) ----------
__global__ __launch_bounds__(512) void part_k(const int* __restrict__ ei, int E, int NB,
                                              int* __restrict__ gcnt,
                                              unsigned* __restrict__ bucket) {
    __shared__ int cnt[512];
    __shared__ int scn[512];
    __shared__ int gbase[512];
    __shared__ unsigned ordered[PCHUNK];        // 32 KB
    __shared__ unsigned short ordK[PCHUNK];     // 16 KB: bucket id per slot
    int t = threadIdx.x;
    int c0 = blockIdx.x * PCHUNK;
    const int* __restrict__ src = ei;
    const int* __restrict__ dst = ei + E;

    cnt[t] = 0;
    __syncthreads();
    for (int i = t; i < PCHUNK; i += 512) {
        int e = c0 + i;
        if (e < E) atomicAdd(&cnt[dst[e] >> BSH], 1);
    }
    __syncthreads();
    scn[t] = cnt[t];
    __syncthreads();
    for (int o = 1; o < 512; o <<= 1) {
        int v = (t >= o) ? scn[t - o] : 0;
        __syncthreads();
        scn[t] += v;
        __syncthreads();
    }
    int ex = scn[t] - cnt[t];
    __syncthreads();
    scn[t] = ex;                             // exclusive scan
    int cn = cnt[t];
    gbase[t] = (t < NB && cn > 0) ? atomicAdd(&gcnt[t], cn) : 0;
    __syncthreads();
    cnt[t] = 0;
    __syncthreads();
    for (int i = t; i < PCHUNK; i += 512) {
        int e = c0 + i;
        if (e < E) {
            int s = src[e], d = dst[e];
            int k = d >> BSH;
            int slot = scn[k] + atomicAdd(&cnt[k], 1);
            ordered[slot] = (unsigned)s | ((unsigned)(d & 255) << 24);
            ordK[slot] = (unsigned short)k;
        }
    }
    __syncthreads();
    int tot = scn[511] + cnt[511];
    for (int i = t; i < tot; i += 512) {
        int k = ordK[i];
        bucket[(size_t)k * BCAP + gbase[k] + (i - scn[k])] = ordered[i];
    }
}

// ---------- 2. per-bucket: degree count + LDS counting sort -> dense CSR ----------
__global__ __launch_bounds__(256) void sort_k(unsigned* __restrict__ bucket,
                                              const int* __restrict__ gcnt,
                                              int* __restrict__ deg,
                                              float* __restrict__ dinv,
                                              int* __restrict__ off, int n) {
    __shared__ int cnt[256];
    __shared__ int excl[256];
    __shared__ int cur[256];
    __shared__ int ordered[BCAP];            // 35 KB
    int bk = blockIdx.x;
    int t = threadIdx.x;
    int node0 = bk << BSH;
    cnt[t] = 0;
    __syncthreads();
    int ecnt = gcnt[bk];
    unsigned* __restrict__ bb = bucket + (size_t)bk * BCAP;
    for (int i = t; i < ecnt; i += 256) {
        unsigned p = bb[i];
        atomicAdd(&cnt[p >> 24], 1);
    }
    __syncthreads();
    int dg = cnt[t];
    excl[t] = dg;
    __syncthreads();
    for (int o = 1; o < 256; o <<= 1) {
        int v = (t >= o) ? excl[t - o] : 0;
        __syncthreads();
        excl[t] += v;
        __syncthreads();
    }
    int ex = excl[t] - dg;                   // exclusive
    __syncthreads();
    excl[t] = ex;
    cur[t] = 0;
    int node = node0 + t;
    if (node < n) {
        deg[node]  = dg;
        dinv[node] = rsqrtf((float)dg + 1.0f);   // +1 self-loop
        off[node]  = bk * BCAP + ex;             // csr int-index base
    }
    __syncthreads();
    for (int i = t; i < ecnt; i += 256) {
        unsigned p = bb[i];
        int s = (int)(p & 0xFFFFFFu), d = (int)(p >> 24);
        int slot = excl[d] + atomicAdd(&cur[d], 1);
        ordered[slot] = s;
    }
    __syncthreads();
    int* __restrict__ csr = (int*)bb;
    for (int i = t; i < ecnt; i += 256) csr[i] = ordered[i];
}

// ---------- 3. h1' = dinv * (x @ W1) -> fp8, via MFMA f16 (128 nodes/block) ----------
#define LDK 136
__global__ __launch_bounds__(512) void gemm1_k(const float* __restrict__ x,
                                               const float* __restrict__ W,
                                               const float* __restrict__ dinv,
                                               unsigned char* __restrict__ h, int n) {
    __shared__ __align__(16) float uShared[128 * 68];  // 34816B: xs f16 overlay, then outS f32
    __shared__ __align__(16) _Float16 Wt[64 * LDK];    // 17408B: W^T f16
    int t = threadIdx.x;
    int node0 = blockIdx.x * 128;
    _Float16* xs = (_Float16*)uShared;

    // stage x tile: 128 rows x 128 cols fp32 -> f16 (coalesced float4 loads)
    for (int i = t; i < 128 * 32; i += 512) {
        int row = i >> 5, c4 = i & 31;
        int node = node0 + row;
        float4 v = (node < n) ? *(const float4*)(x + (size_t)node * IN_CH + c4 * 4)
                              : make_float4(0.f, 0.f, 0.f, 0.f);
        _Float16* dstp = xs + row * LDK + c4 * 4;
        dstp[0] = (_Float16)v.x; dstp[1] = (_Float16)v.y;
        dstp[2] = (_Float16)v.z; dstp[3] = (_Float16)v.w;
    }
    // stage W^T: W[k][nn] -> Wt[nn][k]
    for (int i = t; i < IN_CH * HID_CH; i += 512) {
        int k = i >> 6, nn = i & 63;
        Wt[nn * LDK + k] = (_Float16)W[i];
    }
    __syncthreads();

    int w = t >> 6, lane = t & 63;           // 8 waves; wave w owns rows 16w..16w+15
    int rsel = lane & 15, ksel = lane >> 4;
    f32x4 acc[4];
#pragma unroll
    for (int ct = 0; ct < 4; ++ct) acc[ct] = (f32x4){0.f, 0.f, 0.f, 0.f};

#pragma unroll
    for (int kk = 0; kk < 4; ++kk) {
        f16x8 a = *(const f16x8*)(xs + (16 * w + rsel) * LDK + kk * 32 + ksel * 8);
#pragma unroll
        for (int ct = 0; ct < 4; ++ct) {
            f16x8 b = *(const f16x8*)(Wt + (ct * 16 + rsel) * LDK + kk * 32 + ksel * 8);
            acc[ct] = __builtin_amdgcn_mfma_f32_16x16x32_f16(a, b, acc[ct], 0, 0, 0);
        }
    }
    __syncthreads();                       // xs dead; overlay outS
    float* outS = uShared;
#pragma unroll
    for (int ct = 0; ct < 4; ++ct)
#pragma unroll
        for (int r = 0; r < 4; ++r)
            outS[(16 * w + ksel * 4 + r) * 68 + ct * 16 + rsel] = acc[ct][r];
    __syncthreads();

    // epilogue: dinv-scale -> fp8, coalesced 16B stores (4 threads per row)
    {
        int row = t >> 2, quad = t & 3;      // 512/4 = 128 rows
        int node = node0 + row;
        if (node < n) {
            float dv = dinv[node];
            const float* srcp = outS + row * 68 + quad * 16;
            unsigned un[4];
#pragma unroll
            for (int g = 0; g < 4; ++g) {
                unsigned v = 0;
#pragma unroll
                for (int j = 0; j < 4; ++j)
                    v |= (unsigned)f2fp8(srcp[g * 4 + j] * dv) << (8 * j);
                un[g] = v;
            }
            *(uint4*)(h + (size_t)node * HID_CH + quad * 16) = make_uint4(un[0], un[1], un[2], un[3]);
        }
    }
}

// ---------- 4. layer-1 gather: e8 x cg8 wide loads + 4-deep unroll -> z fp16 ----------
__global__ __launch_bounds__(256) void agg1_gather_k(const int* __restrict__ off,
                                                     const int* __restrict__ deg,
                                                     const int* __restrict__ csr,
                                                     const float* __restrict__ dinv,
                                                     const unsigned char* __restrict__ h,
                                                     const float* __restrict__ b1,
                                                     __half* __restrict__ z, int n) {
    int tid = threadIdx.x;
    int node = blockIdx.x * 4 + (tid >> 6);
    if (node >= n) return;
    int lane = tid & 63;
    int e8 = lane >> 3, cg = lane & 7;

    float acc[8];
#pragma unroll
    for (int j = 0; j < 8; ++j) acc[j] = 0.0f;

    if (e8 == 0)   // self-loop row
        acc8(acc, *(const ull*)(h + (size_t)node * HID_CH + cg * 8));

    int o = off[node], end = o + deg[node];
    int i = o + e8;
    for (; i + 24 < end; i += 32) {
        int s0 = csr[i], s1 = csr[i + 8], s2 = csr[i + 16], s3 = csr[i + 24];
        ull p0 = *(const ull*)(h + (size_t)s0 * HID_CH + cg * 8);
        ull p1 = *(const ull*)(h + (size_t)s1 * HID_CH + cg * 8);
        ull p2 = *(const ull*)(h + (size_t)s2 * HID_CH + cg * 8);
        ull p3 = *(const ull*)(h + (size_t)s3 * HID_CH + cg * 8);
        acc8(acc, p0); acc8(acc, p1); acc8(acc, p2); acc8(acc, p3);
    }
    for (; i < end; i += 8)
        acc8(acc, *(const ull*)(h + (size_t)csr[i] * HID_CH + cg * 8));

    // reduce across edge-slots (same cg): xor 8,16,32
#pragma unroll
    for (int j = 0; j < 8; ++j) {
        acc[j] += __shfl_xor(acc[j], 8);
        acc[j] += __shfl_xor(acc[j], 16);
        acc[j] += __shfl_xor(acc[j], 32);
    }

    if (e8 == 0) {
        float dv = dinv[node];
        union { __half2 hv[4]; uint4 u; } pk;
#pragma unroll
        for (int j2 = 0; j2 < 4; ++j2) {
            float z0 = fmaxf(dv * acc[2 * j2]      + b1[cg * 8 + 2 * j2],     0.0f);
            float z1v = fmaxf(dv * acc[2 * j2 + 1] + b1[cg * 8 + 2 * j2 + 1], 0.0f);
            pk.hv[j2] = __floats2half2_rn(z0, z1v);
        }
        *(uint4*)(z + (size_t)node * HID_CH + cg * 8) = pk.u;
    }
}

// ---------- 5. h2' = dinv * (z @ W2) -> fp16 ----------
__global__ __launch_bounds__(256) void gemm2_k(const __half* __restrict__ z,
                                               const float* __restrict__ W,
                                               const float* __restrict__ dinv,
                                               __half* __restrict__ h2, int n) {
    __shared__ float Ws[HID_CH * OUT_CH];
    int tid = threadIdx.x;
    for (int i = tid; i < HID_CH * OUT_CH; i += 256) Ws[i] = W[i];
    __syncthreads();
    int node = blockIdx.x * 256 + tid;
    if (node >= n) return;
    float acc[OUT_CH];
#pragma unroll
    for (int c = 0; c < OUT_CH; ++c) acc[c] = 0.0f;
    const __half2* zr = (const __half2*)(z + (size_t)node * HID_CH);
#pragma unroll 8
    for (int k2 = 0; k2 < HID_CH / 2; ++k2) {
        float2 v = __half22float2(zr[k2]);
        int k = k2 * 2;
#pragma unroll
        for (int c = 0; c < OUT_CH; ++c)
            acc[c] += v.x * Ws[k * OUT_CH + c] + v.y * Ws[(k + 1) * OUT_CH + c];
    }
    float dv = dinv[node];
    __half2* o2 = (__half2*)(h2 + (size_t)node * OUT_CH);
#pragma unroll
    for (int c2 = 0; c2 < OUT_CH / 2; ++c2)
        o2[c2] = __floats2half2_rn(dv * acc[2 * c2], dv * acc[2 * c2 + 1]);
}

// ---------- 6. layer-2 gather: 16 lanes/node, 16B row per edge + log_softmax ----------
// lane = (node_sub = lane>>4, s16 = lane&15). One VMEM covers a full h2 row.
__global__ __launch_bounds__(256) void agg2_final_k(const int* __restrict__ off,
                                                    const int* __restrict__ deg,
                                                    const int* __restrict__ csr,
                                                    const float* __restrict__ dinv,
                                                    const __half* __restrict__ h2,
                                                    const float* __restrict__ b,
                                                    float* __restrict__ out, int n) {
    int tid = threadIdx.x;
    int node = blockIdx.x * 16 + (tid >> 4);
    if (node >= n) return;
    int s16 = tid & 15;

    float acc[8];
#pragma unroll
    for (int c = 0; c < 8; ++c) acc[c] = 0.0f;

    auto addrow = [&](const __half* rp) {
        uint4 u = *(const uint4*)rp;
        union { uint4 u; __half2 hv[4]; } cv; cv.u = u;
#pragma unroll
        for (int q = 0; q < 4; ++q) {
            float2 f = __half22float2(cv.hv[q]);
            acc[2 * q]     += f.x;
            acc[2 * q + 1] += f.y;
        }
    };

    if (s16 == 0) addrow(h2 + (size_t)node * OUT_CH);   // self-loop

    int o = off[node], end = o + deg[node];
    int i = o + s16;
    for (; i + 16 < end; i += 32) {                      // 2-deep unroll
        int s0 = csr[i], s1 = csr[i + 16];
        const __half* r0 = h2 + (size_t)s0 * OUT_CH;
        const __half* r1 = h2 + (size_t)s1 * OUT_CH;
        uint4 u0 = *(const uint4*)r0;
        uint4 u1 = *(const uint4*)r1;
        union { uint4 u; __half2 hv[4]; } c0, c1; c0.u = u0; c1.u = u1;
#pragma unroll
        for (int q = 0; q < 4; ++q) {
            float2 f0 = __half22float2(c0.hv[q]);
            float2 f1 = __half22float2(c1.hv[q]);
            acc[2 * q]     += f0.x + f1.x;
            acc[2 * q + 1] += f0.y + f1.y;
        }
    }
    for (; i < end; i += 16) addrow(h2 + (size_t)csr[i] * OUT_CH);

    // reduce across the 16 edge-slots: xor 1,2,4,8 (within the 16-lane group)
#pragma unroll
    for (int c = 0; c < 8; ++c) {
        acc[c] += __shfl_xor(acc[c], 1);
        acc[c] += __shfl_xor(acc[c], 2);
        acc[c] += __shfl_xor(acc[c], 4);
        acc[c] += __shfl_xor(acc[c], 8);
    }

    if (s16 == 0) {
        float dv = dinv[node];
        float val[8];
        float m = -1e30f;
#pragma unroll
        for (int c = 0; c < 8; ++c) {
            val[c] = dv * acc[c] + b[c];
            m = fmaxf(m, val[c]);
        }
        float s = 0.0f;
#pragma unroll
        for (int c = 0; c < 8; ++c) s += expf(val[c] - m);
        float lse = m + logf(s);
        float4 o0 = make_float4(val[0] - lse, val[1] - lse, val[2] - lse, val[3] - lse);
        float4 o1 = make_float4(val[4] - lse, val[5] - lse, val[6] - lse, val[7] - lse);
        float* op = out + (size_t)node * OUT_CH;
        *(float4*)op = o0;
        *(float4*)(op + 4) = o1;
    }
}

extern "C" void kernel_launch(void* const* d_in, const int* in_sizes, int n_in,
                              void* d_out, int out_size, void* d_ws, size_t ws_size,
                              hipStream_t stream) {
    const float* x  = (const float*)d_in[0];
    const int*   ei = (const int*)d_in[1];
    const float* W1 = (const float*)d_in[2];
    const float* b1 = (const float*)d_in[3];
    const float* W2 = (const float*)d_in[4];
    const float* b2 = (const float*)d_in[5];
    float* out = (float*)d_out;

    const int n = in_sizes[0] / IN_CH;      // 100000
    const int E = in_sizes[1] / 2;          // 3200000
    const int NP = 100352;
    const int NB = (n + 255) >> BSH;        // 391 buckets

    // ---- workspace layout (~36 MB) ----
    int*      deg    = (int*)d_ws;                              // [NP]
    float*    dinv   = (float*)(deg + NP);                      // [NP]
    int*      gcnt   = (int*)(dinv + NP);                       // [512]
    int*      off    = gcnt + 512;                              // [NP]
    unsigned* bucket = (unsigned*)(off + NP);                   // [NB*BCAP] u32 = 14 MB
    unsigned char* h1 = (unsigned char*)(bucket + (size_t)NB * BCAP); // [NP*64] fp8
    __half*   z1     = (__half*)(h1 + (size_t)NP * HID_CH);     // [NP*64] fp16
    __half*   h2     = z1 + (size_t)NP * HID_CH;                // [NP*8] fp16
    int*      csr    = (int*)bucket;                            // sorted src ids after sort_k

    const int NCH = (E + PCHUNK - 1) / PCHUNK;                  // 391 partition blocks

    hipMemsetAsync(gcnt, 0, 512 * sizeof(int), stream);
    part_k<<<NCH, 512, 0, stream>>>(ei, E, NB, gcnt, bucket);
    sort_k<<<NB, 256, 0, stream>>>(bucket, gcnt, deg, dinv, off, n);
    gemm1_k<<<(n + 127) / 128, 512, 0, stream>>>(x, W1, dinv, h1, n);
    agg1_gather_k<<<(n + 3) / 4, 256, 0, stream>>>(off, deg, csr, dinv, h1, b1, z1, n);
    gemm2_k<<<(n + 255) / 256, 256, 0, stream>>>(z1, W2, dinv, h2, n);
    agg2_final_k<<<(n + 15) / 16, 256, 0, stream>>>(off, deg, csr, dinv, h2, b2, out, n);
}

// Round 22
// 153.372 us; speedup vs baseline: 1.1422x; 1.0330x over previous
//
#include <hip/hip_runtime.h>
#include <hip/hip_fp16.h>
#include <hip/hip_fp8.h>

#define IN_CH  128
#define HID_CH 64
#define OUT_CH 8
#define BSH    8        // 256 nodes per bucket
#define BCAP   11264    // per-bucket capacity (8192 mean + 6sigma + 1792 max pad)
#define PCHUNK 8192     // edges per partition block

typedef unsigned long long ull;
typedef float floatx2 __attribute__((ext_vector_type(2)));
typedef _Float16 f16x8 __attribute__((ext_vector_type(8)));
typedef float f32x4 __attribute__((ext_vector_type(4)));

// edge_index arrives as int32. src = ei[0..E), dst = ei[E..2E).
// packed edge: low bits = src, bits 24..31 = dst & 255
// CSR lists are PADDED to a multiple of 8 with sentinel src = n (zero row).

__device__ __forceinline__ unsigned char f2fp8(float f) {
    __hip_fp8_e4m3 t(f);
    return (unsigned char)t.__x;
}

// unpack 8 fp8 bytes -> 8 floats via packed HW converts
__device__ __forceinline__ void acc8(float* acc, ull p) {
#if __has_builtin(__builtin_amdgcn_cvt_pk_f32_fp8)
    unsigned lo = (unsigned)p, hi = (unsigned)(p >> 32);
    floatx2 q0 = __builtin_amdgcn_cvt_pk_f32_fp8(lo, false);
    floatx2 q1 = __builtin_amdgcn_cvt_pk_f32_fp8(lo, true);
    floatx2 q2 = __builtin_amdgcn_cvt_pk_f32_fp8(hi, false);
    floatx2 q3 = __builtin_amdgcn_cvt_pk_f32_fp8(hi, true);
    acc[0] += q0.x; acc[1] += q0.y; acc[2] += q1.x; acc[3] += q1.y;
    acc[4] += q2.x; acc[5] += q2.y; acc[6] += q3.x; acc[7] += q3.y;
#else
    __hip_fp8_e4m3 t;
#pragma unroll
    for (int j = 0; j < 8; ++j) { t.__x = (__hip_fp8_storage_t)(p >> (8 * j)); acc[j] += (float)t; }
#endif
}

// ---------- 1. coarse partition into 256-node buckets (dense-run writes) ----------
__global__ __launch_bounds__(512) void part_k(const int* __restrict__ ei, int E, int NB,
                                              int* __restrict__ gcnt,
                                              unsigned* __restrict__ bucket) {
    __shared__ int cnt[512];
    __shared__ int scn[512];
    __shared__ int gbase[512];
    __shared__ unsigned ordered[PCHUNK];        // 32 KB
    __shared__ unsigned short ordK[PCHUNK];     // 16 KB: bucket id per slot
    int t = threadIdx.x;
    int c0 = blockIdx.x * PCHUNK;
    const int* __restrict__ src = ei;
    const int* __restrict__ dst = ei + E;

    cnt[t] = 0;
    __syncthreads();
    for (int i = t; i < PCHUNK; i += 512) {
        int e = c0 + i;
        if (e < E) atomicAdd(&cnt[dst[e] >> BSH], 1);
    }
    __syncthreads();
    scn[t] = cnt[t];
    __syncthreads();
    for (int o = 1; o < 512; o <<= 1) {
        int v = (t >= o) ? scn[t - o] : 0;
        __syncthreads();
        scn[t] += v;
        __syncthreads();
    }
    int ex = scn[t] - cnt[t];
    __syncthreads();
    scn[t] = ex;                             // exclusive scan
    int cn = cnt[t];
    gbase[t] = (t < NB && cn > 0) ? atomicAdd(&gcnt[t], cn) : 0;
    __syncthreads();
    cnt[t] = 0;
    __syncthreads();
    for (int i = t; i < PCHUNK; i += 512) {
        int e = c0 + i;
        if (e < E) {
            int s = src[e], d = dst[e];
            int k = d >> BSH;
            int slot = scn[k] + atomicAdd(&cnt[k], 1);
            ordered[slot] = (unsigned)s | ((unsigned)(d & 255) << 24);
            ordK[slot] = (unsigned short)k;
        }
    }
    __syncthreads();
    int tot = scn[511] + cnt[511];
    for (int i = t; i < tot; i += 512) {
        int k = ordK[i];
        bucket[(size_t)k * BCAP + gbase[k] + (i - scn[k])] = ordered[i];
    }
}

// ---------- 2. per-bucket: degree count + LDS counting sort -> PADDED dense CSR ----------
// deg[] receives the PADDED degree (multiple of 8); dinv uses the real degree.
// Pad slots hold sentinel src = n, whose h1/h2 rows are zeroed.
__global__ __launch_bounds__(256) void sort_k(unsigned* __restrict__ bucket,
                                              const int* __restrict__ gcnt,
                                              int* __restrict__ deg,
                                              float* __restrict__ dinv,
                                              int* __restrict__ off, int n) {
    __shared__ int cnt[256];
    __shared__ int excl[256];
    __shared__ int cur[256];
    __shared__ int tot_s;
    __shared__ int ordered[BCAP];            // 44 KB
    int bk = blockIdx.x;
    int t = threadIdx.x;
    int node0 = bk << BSH;
    cnt[t] = 0;
    __syncthreads();
    int ecnt = gcnt[bk];
    unsigned* __restrict__ bb = bucket + (size_t)bk * BCAP;
    for (int i = t; i < ecnt; i += 256) {
        unsigned p = bb[i];
        atomicAdd(&cnt[p >> 24], 1);
    }
    __syncthreads();
    int dg = cnt[t];
    int pdg = (dg + 7) & ~7;                 // padded to multiple of 8
    // inclusive scan of PADDED degrees
    excl[t] = pdg;
    __syncthreads();
    for (int o = 1; o < 256; o <<= 1) {
        int v = (t >= o) ? excl[t - o] : 0;
        __syncthreads();
        excl[t] += v;
        __syncthreads();
    }
    int exp_ = excl[t] - pdg;                // exclusive padded offset
    if (t == 255) tot_s = exp_ + pdg;
    __syncthreads();
    excl[t] = exp_;
    cur[t] = 0;
    int node = node0 + t;
    if (node < n) {
        deg[node]  = pdg;                    // padded count for gather loops
        dinv[node] = rsqrtf((float)dg + 1.0f);   // +1 self-loop (REAL degree)
        off[node]  = bk * BCAP + exp_;       // csr int-index base
    }
    __syncthreads();
    for (int i = t; i < ecnt; i += 256) {
        unsigned p = bb[i];
        int s = (int)(p & 0xFFFFFFu), d = (int)(p >> 24);
        int slot = excl[d] + atomicAdd(&cur[d], 1);
        ordered[slot] = s;
    }
    // fill pad slots with sentinel (disjoint from scatter slots)
    for (int p = dg; p < pdg; ++p) ordered[exp_ + p] = n;
    __syncthreads();
    int tot = tot_s;
    int* __restrict__ csr = (int*)bb;
    for (int i = t; i < tot; i += 256) csr[i] = ordered[i];
}

// ---------- 3. h1' = dinv * (x @ W1) -> fp8, via MFMA f16 (128 nodes/block) ----------
#define LDK 136
__global__ __launch_bounds__(512) void gemm1_k(const float* __restrict__ x,
                                               const float* __restrict__ W,
                                               const float* __restrict__ dinv,
                                               unsigned char* __restrict__ h, int n) {
    __shared__ __align__(16) float uShared[128 * 68];  // xs f16 overlay, then outS f32
    __shared__ __align__(16) _Float16 Wt[64 * LDK];    // W^T f16
    int t = threadIdx.x;
    int node0 = blockIdx.x * 128;
    _Float16* xs = (_Float16*)uShared;

    for (int i = t; i < 128 * 32; i += 512) {
        int row = i >> 5, c4 = i & 31;
        int node = node0 + row;
        float4 v = (node < n) ? *(const float4*)(x + (size_t)node * IN_CH + c4 * 4)
                              : make_float4(0.f, 0.f, 0.f, 0.f);
        _Float16* dstp = xs + row * LDK + c4 * 4;
        dstp[0] = (_Float16)v.x; dstp[1] = (_Float16)v.y;
        dstp[2] = (_Float16)v.z; dstp[3] = (_Float16)v.w;
    }
    for (int i = t; i < IN_CH * HID_CH; i += 512) {
        int k = i >> 6, nn = i & 63;
        Wt[nn * LDK + k] = (_Float16)W[i];
    }
    __syncthreads();

    int w = t >> 6, lane = t & 63;
    int rsel = lane & 15, ksel = lane >> 4;
    f32x4 acc[4];
#pragma unroll
    for (int ct = 0; ct < 4; ++ct) acc[ct] = (f32x4){0.f, 0.f, 0.f, 0.f};

#pragma unroll
    for (int kk = 0; kk < 4; ++kk) {
        f16x8 a = *(const f16x8*)(xs + (16 * w + rsel) * LDK + kk * 32 + ksel * 8);
#pragma unroll
        for (int ct = 0; ct < 4; ++ct) {
            f16x8 b = *(const f16x8*)(Wt + (ct * 16 + rsel) * LDK + kk * 32 + ksel * 8);
            acc[ct] = __builtin_amdgcn_mfma_f32_16x16x32_f16(a, b, acc[ct], 0, 0, 0);
        }
    }
    __syncthreads();
    float* outS = uShared;
#pragma unroll
    for (int ct = 0; ct < 4; ++ct)
#pragma unroll
        for (int r = 0; r < 4; ++r)
            outS[(16 * w + ksel * 4 + r) * 68 + ct * 16 + rsel] = acc[ct][r];
    __syncthreads();

    {
        int row = t >> 2, quad = t & 3;
        int node = node0 + row;
        if (node < n) {
            float dv = dinv[node];
            const float* srcp = outS + row * 68 + quad * 16;
            unsigned un[4];
#pragma unroll
            for (int g = 0; g < 4; ++g) {
                unsigned v = 0;
#pragma unroll
                for (int j = 0; j < 4; ++j)
                    v |= (unsigned)f2fp8(srcp[g * 4 + j] * dv) << (8 * j);
                un[g] = v;
            }
            *(uint4*)(h + (size_t)node * HID_CH + quad * 16) = make_uint4(un[0], un[1], un[2], un[3]);
        }
    }
}

// ---------- 4. layer-1 gather: e8 x cg8, padded lists -> uniform loop counts ----------
__global__ __launch_bounds__(256) void agg1_gather_k(const int* __restrict__ off,
                                                     const int* __restrict__ deg,
                                                     const int* __restrict__ csr,
                                                     const float* __restrict__ dinv,
                                                     const unsigned char* __restrict__ h,
                                                     const float* __restrict__ b1,
                                                     __half* __restrict__ z, int n) {
    int tid = threadIdx.x;
    int node = blockIdx.x * 4 + (tid >> 6);
    if (node >= n) return;
    int lane = tid & 63;
    int e8 = lane >> 3, cg = lane & 7;

    float acc[8];
#pragma unroll
    for (int j = 0; j < 8; ++j) acc[j] = 0.0f;

    if (e8 == 0)   // self-loop row
        acc8(acc, *(const ull*)(h + (size_t)node * HID_CH + cg * 8));

    int o = off[node];
    int m = deg[node] >> 3;                  // slots per lane (deg padded to 8)
    int k4 = m >> 2, rem = m & 3;
    int i = o + e8;
    for (int it = 0; it < k4; ++it, i += 32) {
        int s0 = csr[i], s1 = csr[i + 8], s2 = csr[i + 16], s3 = csr[i + 24];
        ull p0 = *(const ull*)(h + (size_t)s0 * HID_CH + cg * 8);
        ull p1 = *(const ull*)(h + (size_t)s1 * HID_CH + cg * 8);
        ull p2 = *(const ull*)(h + (size_t)s2 * HID_CH + cg * 8);
        ull p3 = *(const ull*)(h + (size_t)s3 * HID_CH + cg * 8);
        acc8(acc, p0); acc8(acc, p1); acc8(acc, p2); acc8(acc, p3);
    }
    for (int r = 0; r < rem; ++r, i += 8)
        acc8(acc, *(const ull*)(h + (size_t)csr[i] * HID_CH + cg * 8));

    // reduce across edge-slots (same cg): xor 8,16,32
#pragma unroll
    for (int j = 0; j < 8; ++j) {
        acc[j] += __shfl_xor(acc[j], 8);
        acc[j] += __shfl_xor(acc[j], 16);
        acc[j] += __shfl_xor(acc[j], 32);
    }

    if (e8 == 0) {
        float dv = dinv[node];
        union { __half2 hv[4]; uint4 u; } pk;
#pragma unroll
        for (int j2 = 0; j2 < 4; ++j2) {
            float z0 = fmaxf(dv * acc[2 * j2]      + b1[cg * 8 + 2 * j2],     0.0f);
            float z1v = fmaxf(dv * acc[2 * j2 + 1] + b1[cg * 8 + 2 * j2 + 1], 0.0f);
            pk.hv[j2] = __floats2half2_rn(z0, z1v);
        }
        *(uint4*)(z + (size_t)node * HID_CH + cg * 8) = pk.u;
    }
}

// ---------- 5. h2' = dinv * (z @ W2) -> fp16 ----------
__global__ __launch_bounds__(256) void gemm2_k(const __half* __restrict__ z,
                                               const float* __restrict__ W,
                                               const float* __restrict__ dinv,
                                               __half* __restrict__ h2, int n) {
    __shared__ float Ws[HID_CH * OUT_CH];
    int tid = threadIdx.x;
    for (int i = tid; i < HID_CH * OUT_CH; i += 256) Ws[i] = W[i];
    __syncthreads();
    int node = blockIdx.x * 256 + tid;
    if (node >= n) return;
    float acc[OUT_CH];
#pragma unroll
    for (int c = 0; c < OUT_CH; ++c) acc[c] = 0.0f;
    const __half2* zr = (const __half2*)(z + (size_t)node * HID_CH);
#pragma unroll 8
    for (int k2 = 0; k2 < HID_CH / 2; ++k2) {
        float2 v = __half22float2(zr[k2]);
        int k = k2 * 2;
#pragma unroll
        for (int c = 0; c < OUT_CH; ++c)
            acc[c] += v.x * Ws[k * OUT_CH + c] + v.y * Ws[(k + 1) * OUT_CH + c];
    }
    float dv = dinv[node];
    __half2* o2 = (__half2*)(h2 + (size_t)node * OUT_CH);
#pragma unroll
    for (int c2 = 0; c2 < OUT_CH / 2; ++c2)
        o2[c2] = __floats2half2_rn(dv * acc[2 * c2], dv * acc[2 * c2 + 1]);
}

// ---------- 6. layer-2 gather: 16 lanes/node, 16B row per edge + log_softmax ----------
__global__ __launch_bounds__(256) void agg2_final_k(const int* __restrict__ off,
                                                    const int* __restrict__ deg,
                                                    const int* __restrict__ csr,
                                                    const float* __restrict__ dinv,
                                                    const __half* __restrict__ h2,
                                                    const float* __restrict__ b,
                                                    float* __restrict__ out, int n) {
    int tid = threadIdx.x;
    int node = blockIdx.x * 16 + (tid >> 4);
    if (node >= n) return;
    int s16 = tid & 15;

    float acc[8];
#pragma unroll
    for (int c = 0; c < 8; ++c) acc[c] = 0.0f;

    auto addrow = [&](const __half* rp) {
        uint4 u = *(const uint4*)rp;
        union { uint4 u; __half2 hv[4]; } cv; cv.u = u;
#pragma unroll
        for (int q = 0; q < 4; ++q) {
            float2 f = __half22float2(cv.hv[q]);
            acc[2 * q]     += f.x;
            acc[2 * q + 1] += f.y;
        }
    };

    if (s16 == 0) addrow(h2 + (size_t)node * OUT_CH);   // self-loop

    int o = off[node], end = o + deg[node];              // padded; pads hit zero row
    int i = o + s16;
    for (; i + 16 < end; i += 32) {
        int s0 = csr[i], s1 = csr[i + 16];
        const __half* r0 = h2 + (size_t)s0 * OUT_CH;
        const __half* r1 = h2 + (size_t)s1 * OUT_CH;
        uint4 u0 = *(const uint4*)r0;
        uint4 u1 = *(const uint4*)r1;
        union { uint4 u; __half2 hv[4]; } c0, c1; c0.u = u0; c1.u = u1;
#pragma unroll
        for (int q = 0; q < 4; ++q) {
            float2 f0 = __half22float2(c0.hv[q]);
            float2 f1 = __half22float2(c1.hv[q]);
            acc[2 * q]     += f0.x + f1.x;
            acc[2 * q + 1] += f0.y + f1.y;
        }
    }
    for (; i < end; i += 16) addrow(h2 + (size_t)csr[i] * OUT_CH);

#pragma unroll
    for (int c = 0; c < 8; ++c) {
        acc[c] += __shfl_xor(acc[c], 1);
        acc[c] += __shfl_xor(acc[c], 2);
        acc[c] += __shfl_xor(acc[c], 4);
        acc[c] += __shfl_xor(acc[c], 8);
    }

    if (s16 == 0) {
        float dv = dinv[node];
        float val[8];
        float m = -1e30f;
#pragma unroll
        for (int c = 0; c < 8; ++c) {
            val[c] = dv * acc[c] + b[c];
            m = fmaxf(m, val[c]);
        }
        float s = 0.0f;
#pragma unroll
        for (int c = 0; c < 8; ++c) s += expf(val[c] - m);
        float lse = m + logf(s);
        float4 o0 = make_float4(val[0] - lse, val[1] - lse, val[2] - lse, val[3] - lse);
        float4 o1 = make_float4(val[4] - lse, val[5] - lse, val[6] - lse, val[7] - lse);
        float* op = out + (size_t)node * OUT_CH;
        *(float4*)op = o0;
        *(float4*)(op + 4) = o1;
    }
}

extern "C" void kernel_launch(void* const* d_in, const int* in_sizes, int n_in,
                              void* d_out, int out_size, void* d_ws, size_t ws_size,
                              hipStream_t stream) {
    const float* x  = (const float*)d_in[0];
    const int*   ei = (const int*)d_in[1];
    const float* W1 = (const float*)d_in[2];
    const float* b1 = (const float*)d_in[3];
    const float* W2 = (const float*)d_in[4];
    const float* b2 = (const float*)d_in[5];
    float* out = (float*)d_out;

    const int n = in_sizes[0] / IN_CH;      // 100000
    const int E = in_sizes[1] / 2;          // 3200000
    const int NP = 100352;
    const int NB = (n + 255) >> BSH;        // 391 buckets

    // ---- workspace layout (~40 MB) ----
    int*      deg    = (int*)d_ws;                              // [NP] (PADDED degrees)
    float*    dinv   = (float*)(deg + NP);                      // [NP]
    int*      gcnt   = (int*)(dinv + NP);                       // [512]
    int*      off    = gcnt + 512;                              // [NP]
    unsigned* bucket = (unsigned*)(off + NP);                   // [NB*BCAP] u32 = 17.6 MB
    unsigned char* h1 = (unsigned char*)(bucket + (size_t)NB * BCAP); // [(NP+1)*64] fp8
    __half*   z1     = (__half*)(h1 + (size_t)(NP + 64) * HID_CH);    // [NP*64] fp16
    __half*   h2     = z1 + (size_t)NP * HID_CH;                // [(NP+1)*8] fp16
    int*      csr    = (int*)bucket;                            // padded sorted src ids

    const int NCH = (E + PCHUNK - 1) / PCHUNK;                  // 391 partition blocks

    hipMemsetAsync(gcnt, 0, 512 * sizeof(int), stream);
    hipMemsetAsync(h1 + (size_t)n * HID_CH, 0, HID_CH, stream);           // zero sentinel h1 row
    hipMemsetAsync(h2 + (size_t)n * OUT_CH, 0, OUT_CH * sizeof(__half), stream); // zero sentinel h2 row
    part_k<<<NCH, 512, 0, stream>>>(ei, E, NB, gcnt, bucket);
    sort_k<<<NB, 256, 0, stream>>>(bucket, gcnt, deg, dinv, off, n);
    gemm1_k<<<(n + 127) / 128, 512, 0, stream>>>(x, W1, dinv, h1, n);
    agg1_gather_k<<<(n + 3) / 4, 256, 0, stream>>>(off, deg, csr, dinv, h1, b1, z1, n);
    gemm2_k<<<(n + 255) / 256, 256, 0, stream>>>(z1, W2, dinv, h2, n);
    agg2_final_k<<<(n + 15) / 16, 256, 0, stream>>>(off, deg, csr, dinv, h2, b2, out, n);
}

// Round 23
// 149.666 us; speedup vs baseline: 1.1704x; 1.0248x over previous
//
#include <hip/hip_runtime.h>
#include <hip/hip_fp16.h>
#include <hip/hip_fp8.h>

#define IN_CH  128
#define HID_CH 64
#define OUT_CH 8
#define BSH    8        // 256 nodes per bucket
#define BCAP   11264    // per-bucket capacity (8192 mean + 6sigma + 1792 max pad)
#define PCHUNK 8192     // edges per partition block

typedef unsigned long long ull;
typedef float floatx2 __attribute__((ext_vector_type(2)));
typedef _Float16 f16x8 __attribute__((ext_vector_type(8)));
typedef float f32x4 __attribute__((ext_vector_type(4)));

// edge_index arrives as int32. src = ei[0..E), dst = ei[E..2E).
// packed edge: low bits = src, bits 24..31 = dst & 255
// CSR lists are PADDED to a multiple of 8 with sentinel src = n (zero row).

__device__ __forceinline__ unsigned char f2fp8(float f) {
    __hip_fp8_e4m3 t(f);
    return (unsigned char)t.__x;
}

// unpack 8 fp8 bytes -> accumulate into acc[8] via packed HW converts
__device__ __forceinline__ void acc8(float* acc, ull p) {
#if __has_builtin(__builtin_amdgcn_cvt_pk_f32_fp8)
    unsigned lo = (unsigned)p, hi = (unsigned)(p >> 32);
    floatx2 q0 = __builtin_amdgcn_cvt_pk_f32_fp8(lo, false);
    floatx2 q1 = __builtin_amdgcn_cvt_pk_f32_fp8(lo, true);
    floatx2 q2 = __builtin_amdgcn_cvt_pk_f32_fp8(hi, false);
    floatx2 q3 = __builtin_amdgcn_cvt_pk_f32_fp8(hi, true);
    acc[0] += q0.x; acc[1] += q0.y; acc[2] += q1.x; acc[3] += q1.y;
    acc[4] += q2.x; acc[5] += q2.y; acc[6] += q3.x; acc[7] += q3.y;
#else
    __hip_fp8_e4m3 t;
#pragma unroll
    for (int j = 0; j < 8; ++j) { t.__x = (__hip_fp8_storage_t)(p >> (8 * j)); acc[j] += (float)t; }
#endif
}

// unpack 8 fp8 bytes -> 8 floats (overwrite)
__device__ __forceinline__ void dec8(float* v, ull p) {
#if __has_builtin(__builtin_amdgcn_cvt_pk_f32_fp8)
    unsigned lo = (unsigned)p, hi = (unsigned)(p >> 32);
    floatx2 q0 = __builtin_amdgcn_cvt_pk_f32_fp8(lo, false);
    floatx2 q1 = __builtin_amdgcn_cvt_pk_f32_fp8(lo, true);
    floatx2 q2 = __builtin_amdgcn_cvt_pk_f32_fp8(hi, false);
    floatx2 q3 = __builtin_amdgcn_cvt_pk_f32_fp8(hi, true);
    v[0] = q0.x; v[1] = q0.y; v[2] = q1.x; v[3] = q1.y;
    v[4] = q2.x; v[5] = q2.y; v[6] = q3.x; v[7] = q3.y;
#else
    __hip_fp8_e4m3 t;
#pragma unroll
    for (int j = 0; j < 8; ++j) { t.__x = (__hip_fp8_storage_t)(p >> (8 * j)); v[j] = (float)t; }
#endif
}

// pack 8 floats -> 8 fp8 bytes
__device__ __forceinline__ ull pack8(const float* v) {
#if __has_builtin(__builtin_amdgcn_cvt_pk_fp8_f32)
    unsigned lo = 0, hi = 0;
    lo = __builtin_amdgcn_cvt_pk_fp8_f32(v[0], v[1], lo, false);
    lo = __builtin_amdgcn_cvt_pk_fp8_f32(v[2], v[3], lo, true);
    hi = __builtin_amdgcn_cvt_pk_fp8_f32(v[4], v[5], hi, false);
    hi = __builtin_amdgcn_cvt_pk_fp8_f32(v[6], v[7], hi, true);
    return (ull)lo | ((ull)hi << 32);
#else
    ull r = 0;
#pragma unroll
    for (int j = 0; j < 8; ++j) r |= (ull)f2fp8(v[j]) << (8 * j);
    return r;
#endif
}

// ---------- 1. coarse partition into 256-node buckets (dense-run writes) ----------
__global__ __launch_bounds__(512) void part_k(const int* __restrict__ ei, int E, int NB,
                                              int* __restrict__ gcnt,
                                              unsigned* __restrict__ bucket) {
    __shared__ int cnt[512];
    __shared__ int scn[512];
    __shared__ int gbase[512];
    __shared__ unsigned ordered[PCHUNK];        // 32 KB
    __shared__ unsigned short ordK[PCHUNK];     // 16 KB: bucket id per slot
    int t = threadIdx.x;
    int c0 = blockIdx.x * PCHUNK;
    const int* __restrict__ src = ei;
    const int* __restrict__ dst = ei + E;

    cnt[t] = 0;
    __syncthreads();
    for (int i = t; i < PCHUNK; i += 512) {
        int e = c0 + i;
        if (e < E) atomicAdd(&cnt[dst[e] >> BSH], 1);
    }
    __syncthreads();
    scn[t] = cnt[t];
    __syncthreads();
    for (int o = 1; o < 512; o <<= 1) {
        int v = (t >= o) ? scn[t - o] : 0;
        __syncthreads();
        scn[t] += v;
        __syncthreads();
    }
    int ex = scn[t] - cnt[t];
    __syncthreads();
    scn[t] = ex;                             // exclusive scan
    int cn = cnt[t];
    gbase[t] = (t < NB && cn > 0) ? atomicAdd(&gcnt[t], cn) : 0;
    __syncthreads();
    cnt[t] = 0;
    __syncthreads();
    for (int i = t; i < PCHUNK; i += 512) {
        int e = c0 + i;
        if (e < E) {
            int s = src[e], d = dst[e];
            int k = d >> BSH;
            int slot = scn[k] + atomicAdd(&cnt[k], 1);
            ordered[slot] = (unsigned)s | ((unsigned)(d & 255) << 24);
            ordK[slot] = (unsigned short)k;
        }
    }
    __syncthreads();
    int tot = scn[511] + cnt[511];
    for (int i = t; i < tot; i += 512) {
        int k = ordK[i];
        bucket[(size_t)k * BCAP + gbase[k] + (i - scn[k])] = ordered[i];
    }
}

// ---------- 2. per-bucket: degree count + LDS counting sort -> PADDED dense CSR ----------
__global__ __launch_bounds__(256) void sort_k(unsigned* __restrict__ bucket,
                                              const int* __restrict__ gcnt,
                                              int* __restrict__ deg,
                                              float* __restrict__ dinv,
                                              int* __restrict__ off, int n) {
    __shared__ int cnt[256];
    __shared__ int excl[256];
    __shared__ int cur[256];
    __shared__ int tot_s;
    __shared__ int ordered[BCAP];            // 44 KB
    int bk = blockIdx.x;
    int t = threadIdx.x;
    int node0 = bk << BSH;
    cnt[t] = 0;
    __syncthreads();
    int ecnt = gcnt[bk];
    unsigned* __restrict__ bb = bucket + (size_t)bk * BCAP;
    for (int i = t; i < ecnt; i += 256) {
        unsigned p = bb[i];
        atomicAdd(&cnt[p >> 24], 1);
    }
    __syncthreads();
    int dg = cnt[t];
    int pdg = (dg + 7) & ~7;                 // padded to multiple of 8
    excl[t] = pdg;
    __syncthreads();
    for (int o = 1; o < 256; o <<= 1) {
        int v = (t >= o) ? excl[t - o] : 0;
        __syncthreads();
        excl[t] += v;
        __syncthreads();
    }
    int exp_ = excl[t] - pdg;                // exclusive padded offset
    if (t == 255) tot_s = exp_ + pdg;
    __syncthreads();
    excl[t] = exp_;
    cur[t] = 0;
    int node = node0 + t;
    if (node < n) {
        deg[node]  = pdg;                    // padded count for gather loops
        dinv[node] = rsqrtf((float)dg + 1.0f);   // +1 self-loop (REAL degree)
        off[node]  = bk * BCAP + exp_;       // csr int-index base
    }
    __syncthreads();
    for (int i = t; i < ecnt; i += 256) {
        unsigned p = bb[i];
        int s = (int)(p & 0xFFFFFFu), d = (int)(p >> 24);
        int slot = excl[d] + atomicAdd(&cur[d], 1);
        ordered[slot] = s;
    }
    for (int p = dg; p < pdg; ++p) ordered[exp_ + p] = n;
    __syncthreads();
    int tot = tot_s;
    int* __restrict__ csr = (int*)bb;
    for (int i = t; i < tot; i += 256) csr[i] = ordered[i];
}

// ---------- 3. h1' = dinv * (x @ W1) -> fp8, via MFMA f16 (128 nodes/block) ----------
#define LDK 136
__global__ __launch_bounds__(512) void gemm1_k(const float* __restrict__ x,
                                               const float* __restrict__ W,
                                               const float* __restrict__ dinv,
                                               unsigned char* __restrict__ h, int n) {
    __shared__ __align__(16) float uShared[128 * 68];  // xs f16 overlay, then outS f32
    __shared__ __align__(16) _Float16 Wt[64 * LDK];    // W^T f16
    int t = threadIdx.x;
    int node0 = blockIdx.x * 128;
    _Float16* xs = (_Float16*)uShared;

    // stage x tile: float4 -> 4 f16 packed -> single 8B LDS store
    for (int i = t; i < 128 * 32; i += 512) {
        int row = i >> 5, c4 = i & 31;
        int node = node0 + row;
        float4 v = (node < n) ? *(const float4*)(x + (size_t)node * IN_CH + c4 * 4)
                              : make_float4(0.f, 0.f, 0.f, 0.f);
        union { _Float16 hf[4]; ull u; } pk;
        pk.hf[0] = (_Float16)v.x; pk.hf[1] = (_Float16)v.y;
        pk.hf[2] = (_Float16)v.z; pk.hf[3] = (_Float16)v.w;
        *(ull*)(xs + row * LDK + c4 * 4) = pk.u;
    }
    for (int i = t; i < IN_CH * HID_CH; i += 512) {
        int k = i >> 6, nn = i & 63;
        Wt[nn * LDK + k] = (_Float16)W[i];
    }
    __syncthreads();

    int w = t >> 6, lane = t & 63;
    int rsel = lane & 15, ksel = lane >> 4;
    f32x4 acc[4];
#pragma unroll
    for (int ct = 0; ct < 4; ++ct) acc[ct] = (f32x4){0.f, 0.f, 0.f, 0.f};

#pragma unroll
    for (int kk = 0; kk < 4; ++kk) {
        f16x8 a = *(const f16x8*)(xs + (16 * w + rsel) * LDK + kk * 32 + ksel * 8);
#pragma unroll
        for (int ct = 0; ct < 4; ++ct) {
            f16x8 b = *(const f16x8*)(Wt + (ct * 16 + rsel) * LDK + kk * 32 + ksel * 8);
            acc[ct] = __builtin_amdgcn_mfma_f32_16x16x32_f16(a, b, acc[ct], 0, 0, 0);
        }
    }
    __syncthreads();
    float* outS = uShared;
#pragma unroll
    for (int ct = 0; ct < 4; ++ct)
#pragma unroll
        for (int r = 0; r < 4; ++r)
            outS[(16 * w + ksel * 4 + r) * 68 + ct * 16 + rsel] = acc[ct][r];
    __syncthreads();

    {
        int row = t >> 2, quad = t & 3;
        int node = node0 + row;
        if (node < n) {
            float dv = dinv[node];
            const float* srcp = outS + row * 68 + quad * 16;
            unsigned un[4];
#pragma unroll
            for (int g = 0; g < 4; ++g) {
                float v4[4];
#pragma unroll
                for (int j = 0; j < 4; ++j) v4[j] = srcp[g * 4 + j] * dv;
                unsigned v = 0;
#pragma unroll
                for (int j = 0; j < 4; ++j) v |= (unsigned)f2fp8(v4[j]) << (8 * j);
                un[g] = v;
            }
            *(uint4*)(h + (size_t)node * HID_CH + quad * 16) = make_uint4(un[0], un[1], un[2], un[3]);
        }
    }
}

// ---------- 4. layer-1 gather: e8 x cg8, padded lists -> z fp8 ----------
__global__ __launch_bounds__(256) void agg1_gather_k(const int* __restrict__ off,
                                                     const int* __restrict__ deg,
                                                     const int* __restrict__ csr,
                                                     const float* __restrict__ dinv,
                                                     const unsigned char* __restrict__ h,
                                                     const float* __restrict__ b1,
                                                     unsigned char* __restrict__ z, int n) {
    int tid = threadIdx.x;
    int node = blockIdx.x * 4 + (tid >> 6);
    if (node >= n) return;
    int lane = tid & 63;
    int e8 = lane >> 3, cg = lane & 7;

    float acc[8];
#pragma unroll
    for (int j = 0; j < 8; ++j) acc[j] = 0.0f;

    if (e8 == 0)   // self-loop row
        acc8(acc, *(const ull*)(h + (size_t)node * HID_CH + cg * 8));

    int o = off[node];
    int m = deg[node] >> 3;                  // slots per lane (deg padded to 8)
    int k4 = m >> 2, rem = m & 3;
    int i = o + e8;
    for (int it = 0; it < k4; ++it, i += 32) {
        int s0 = csr[i], s1 = csr[i + 8], s2 = csr[i + 16], s3 = csr[i + 24];
        ull p0 = *(const ull*)(h + (size_t)s0 * HID_CH + cg * 8);
        ull p1 = *(const ull*)(h + (size_t)s1 * HID_CH + cg * 8);
        ull p2 = *(const ull*)(h + (size_t)s2 * HID_CH + cg * 8);
        ull p3 = *(const ull*)(h + (size_t)s3 * HID_CH + cg * 8);
        acc8(acc, p0); acc8(acc, p1); acc8(acc, p2); acc8(acc, p3);
    }
    for (int r = 0; r < rem; ++r, i += 8)
        acc8(acc, *(const ull*)(h + (size_t)csr[i] * HID_CH + cg * 8));

    // reduce across edge-slots (same cg): xor 8,16,32
#pragma unroll
    for (int j = 0; j < 8; ++j) {
        acc[j] += __shfl_xor(acc[j], 8);
        acc[j] += __shfl_xor(acc[j], 16);
        acc[j] += __shfl_xor(acc[j], 32);
    }

    if (e8 == 0) {
        float dv = dinv[node];
        float zv[8];
#pragma unroll
        for (int j = 0; j < 8; ++j)
            zv[j] = fmaxf(dv * acc[j] + b1[cg * 8 + j], 0.0f);
        *(ull*)(z + (size_t)node * HID_CH + cg * 8) = pack8(zv);
    }
}

// ---------- 5. h2' = dinv * (z @ W2) -> fp16 (z in fp8, 8B loads) ----------
__global__ __launch_bounds__(256) void gemm2_k(const unsigned char* __restrict__ z,
                                               const float* __restrict__ W,
                                               const float* __restrict__ dinv,
                                               __half* __restrict__ h2, int n) {
    __shared__ float Ws[HID_CH * OUT_CH];
    int tid = threadIdx.x;
    for (int i = tid; i < HID_CH * OUT_CH; i += 256) Ws[i] = W[i];
    __syncthreads();
    int node = blockIdx.x * 256 + tid;
    if (node >= n) return;
    float acc[OUT_CH];
#pragma unroll
    for (int c = 0; c < OUT_CH; ++c) acc[c] = 0.0f;
    const ull* zr = (const ull*)(z + (size_t)node * HID_CH);
#pragma unroll
    for (int g = 0; g < 8; ++g) {
        float zv[8];
        dec8(zv, zr[g]);
        int kb = g * 8;
#pragma unroll
        for (int j = 0; j < 8; ++j)
#pragma unroll
            for (int c = 0; c < OUT_CH; ++c)
                acc[c] += zv[j] * Ws[(kb + j) * OUT_CH + c];
    }
    float dv = dinv[node];
    __half2* o2 = (__half2*)(h2 + (size_t)node * OUT_CH);
#pragma unroll
    for (int c2 = 0; c2 < OUT_CH / 2; ++c2)
        o2[c2] = __floats2half2_rn(dv * acc[2 * c2], dv * acc[2 * c2 + 1]);
}

// ---------- 6. layer-2 gather: 16 lanes/node, 16B row per edge + log_softmax ----------
__global__ __launch_bounds__(256) void agg2_final_k(const int* __restrict__ off,
                                                    const int* __restrict__ deg,
                                                    const int* __restrict__ csr,
                                                    const float* __restrict__ dinv,
                                                    const __half* __restrict__ h2,
                                                    const float* __restrict__ b,
                                                    float* __restrict__ out, int n) {
    int tid = threadIdx.x;
    int node = blockIdx.x * 16 + (tid >> 4);
    if (node >= n) return;
    int s16 = tid & 15;

    float acc[8];
#pragma unroll
    for (int c = 0; c < 8; ++c) acc[c] = 0.0f;

    auto addrow = [&](const __half* rp) {
        uint4 u = *(const uint4*)rp;
        union { uint4 u; __half2 hv[4]; } cv; cv.u = u;
#pragma unroll
        for (int q = 0; q < 4; ++q) {
            float2 f = __half22float2(cv.hv[q]);
            acc[2 * q]     += f.x;
            acc[2 * q + 1] += f.y;
        }
    };

    if (s16 == 0) addrow(h2 + (size_t)node * OUT_CH);   // self-loop

    int o = off[node], end = o + deg[node];              // padded; pads hit zero row
    int i = o + s16;
    for (; i + 16 < end; i += 32) {
        int s0 = csr[i], s1 = csr[i + 16];
        const __half* r0 = h2 + (size_t)s0 * OUT_CH;
        const __half* r1 = h2 + (size_t)s1 * OUT_CH;
        uint4 u0 = *(const uint4*)r0;
        uint4 u1 = *(const uint4*)r1;
        union { uint4 u; __half2 hv[4]; } c0, c1; c0.u = u0; c1.u = u1;
#pragma unroll
        for (int q = 0; q < 4; ++q) {
            float2 f0 = __half22float2(c0.hv[q]);
            float2 f1 = __half22float2(c1.hv[q]);
            acc[2 * q]     += f0.x + f1.x;
            acc[2 * q + 1] += f0.y + f1.y;
        }
    }
    for (; i < end; i += 16) addrow(h2 + (size_t)csr[i] * OUT_CH);

#pragma unroll
    for (int c = 0; c < 8; ++c) {
        acc[c] += __shfl_xor(acc[c], 1);
        acc[c] += __shfl_xor(acc[c], 2);
        acc[c] += __shfl_xor(acc[c], 4);
        acc[c] += __shfl_xor(acc[c], 8);
    }

    if (s16 == 0) {
        float dv = dinv[node];
        float val[8];
        float m = -1e30f;
#pragma unroll
        for (int c = 0; c < 8; ++c) {
            val[c] = dv * acc[c] + b[c];
            m = fmaxf(m, val[c]);
        }
        float s = 0.0f;
#pragma unroll
        for (int c = 0; c < 8; ++c) s += expf(val[c] - m);
        float lse = m + logf(s);
        float4 o0 = make_float4(val[0] - lse, val[1] - lse, val[2] - lse, val[3] - lse);
        float4 o1 = make_float4(val[4] - lse, val[5] - lse, val[6] - lse, val[7] - lse);
        float* op = out + (size_t)node * OUT_CH;
        *(float4*)op = o0;
        *(float4*)(op + 4) = o1;
    }
}

extern "C" void kernel_launch(void* const* d_in, const int* in_sizes, int n_in,
                              void* d_out, int out_size, void* d_ws, size_t ws_size,
                              hipStream_t stream) {
    const float* x  = (const float*)d_in[0];
    const int*   ei = (const int*)d_in[1];
    const float* W1 = (const float*)d_in[2];
    const float* b1 = (const float*)d_in[3];
    const float* W2 = (const float*)d_in[4];
    const float* b2 = (const float*)d_in[5];
    float* out = (float*)d_out;

    const int n = in_sizes[0] / IN_CH;      // 100000
    const int E = in_sizes[1] / 2;          // 3200000
    const int NP = 100352;
    const int NB = (n + 255) >> BSH;        // 391 buckets

    // ---- workspace layout (~34 MB) ----
    int*      deg    = (int*)d_ws;                              // [NP] (PADDED degrees)
    float*    dinv   = (float*)(deg + NP);                      // [NP]
    int*      gcnt   = (int*)(dinv + NP);                       // [512]
    int*      off    = gcnt + 512;                              // [NP]
    unsigned* bucket = (unsigned*)(off + NP);                   // [NB*BCAP] u32 = 17.6 MB
    unsigned char* h1 = (unsigned char*)(bucket + (size_t)NB * BCAP); // [(NP+64)*64] fp8
    unsigned char* z1 = h1 + (size_t)(NP + 64) * HID_CH;        // [NP*64] fp8
    __half*   h2     = (__half*)(z1 + (size_t)NP * HID_CH);     // [(NP+1)*8] fp16
    int*      csr    = (int*)bucket;                            // padded sorted src ids

    const int NCH = (E + PCHUNK - 1) / PCHUNK;                  // 391 partition blocks

    hipMemsetAsync(gcnt, 0, 512 * sizeof(int), stream);
    hipMemsetAsync(h1 + (size_t)n * HID_CH, 0, HID_CH, stream);           // zero sentinel h1 row
    hipMemsetAsync(h2 + (size_t)n * OUT_CH, 0, OUT_CH * sizeof(__half), stream); // zero sentinel h2 row
    part_k<<<NCH, 512, 0, stream>>>(ei, E, NB, gcnt, bucket);
    sort_k<<<NB, 256, 0, stream>>>(bucket, gcnt, deg, dinv, off, n);
    gemm1_k<<<(n + 127) / 128, 512, 0, stream>>>(x, W1, dinv, h1, n);
    agg1_gather_k<<<(n + 3) / 4, 256, 0, stream>>>(off, deg, csr, dinv, h1, b1, z1, n);
    gemm2_k<<<(n + 255) / 256, 256, 0, stream>>>(z1, W2, dinv, h2, n);
    agg2_final_k<<<(n + 15) / 16, 256, 0, stream>>>(off, deg, csr, dinv, h2, b2, out, n);
}